// Round 4
// baseline (673.395 us; speedup 1.0000x reference)
//
#include <hip/hip_runtime.h>
#include <hip/hip_bf16.h>
#include <cstdint>

typedef unsigned short u16;
typedef __attribute__((ext_vector_type(8))) short bf16x8;
typedef __attribute__((ext_vector_type(4))) float f32x4;

__device__ __forceinline__ u16 f2b(float f) {
  union { float f; unsigned u; } x; x.f = f;
  unsigned r = x.u + 0x7fffu + ((x.u >> 16) & 1u);   // RNE
  return (u16)(r >> 16);
}
__device__ __forceinline__ void gld16(void* lds, const void* g) {
  __builtin_amdgcn_global_load_lds((const __attribute__((address_space(1))) void*)g,
                                   (__attribute__((address_space(3))) void*)lds, 16, 0, 0);
}
__device__ __forceinline__ int sw_idx(int n, int c) {
  return n * 64 + ((((c >> 2) ^ (n >> 2)) & 15) << 2) + (c & 3);
}

// ---------------------------------------------------------------------------
// prep: blk<512  : reorder+convert w_qkv k/v rows -> wkv_r[h][{k64|v64}][512] bf16
//       blk<576  : transpose-convert w_qkv q rows -> wqT bf16 [i][ch]
//       else     : zero ctx (64*64*80 floats)
// ---------------------------------------------------------------------------
__global__ __launch_bounds__(256) void prep(const float* __restrict__ w_qkv,
                                            u16* __restrict__ wkv_r,
                                            u16* __restrict__ wqT,
                                            float* __restrict__ ctx) {
  const int tid = threadIdx.x;
  const int blk = blockIdx.x;
  if (blk < 512) {
    const int o = blk * 2 + (tid >> 7);       // output row 0..1023
    const int col = (tid & 127) * 4;
    const int h = o >> 7, part = (o & 127) >> 6, c = o & 63;
    const int src = 512 + part * 512 + h * 64 + c;
    const float4 v = *(const float4*)(w_qkv + src * 512 + col);
    ushort4 r; r.x = f2b(v.x); r.y = f2b(v.y); r.z = f2b(v.z); r.w = f2b(v.w);
    *(ushort4*)(wkv_r + o * 512 + col) = r;
  } else if (blk < 576) {
    __shared__ u16 t[4096];
    const int bb = blk - 512;
    const int i0 = (bb & 7) * 64;
    const int c0 = (bb >> 3) * 64;
    const int il = (tid & 15) * 4;
    const int cl = tid >> 4;
#pragma unroll
    for (int r = 0; r < 4; r++) {
      const int c = cl + r * 16;
      const float4 v = *(const float4*)(w_qkv + (c0 + c) * 512 + i0 + il);
      t[sw_idx(il + 0, c)] = f2b(v.x);
      t[sw_idx(il + 1, c)] = f2b(v.y);
      t[sw_idx(il + 2, c)] = f2b(v.z);
      t[sw_idx(il + 3, c)] = f2b(v.w);
    }
    __syncthreads();
    const int cw = (tid & 15) * 4;
#pragma unroll
    for (int r = 0; r < 4; r++) {
      const int i = cl + r * 16;
      const u16* tp = &t[sw_idx(i, cw)];
      ushort4 o; o.x = tp[0]; o.y = tp[1]; o.z = tp[2]; o.w = tp[3];
      *(ushort4*)(wqT + (i0 + i) * 512 + c0 + cw) = o;
    }
  } else {
    const int zi = (blk - 576) * 1024 + tid * 4;
    if (zi < 327680) *(float4*)(ctx + zi) = float4{0.f, 0.f, 0.f, 0.f};
  }
}

// ---------------------------------------------------------------------------
// xt: transpose-convert x [b][512][4096] fp32 -> xt [b][4096][512] bf16
// ---------------------------------------------------------------------------
__global__ __launch_bounds__(256) void xt_kern(const float* __restrict__ x,
                                               u16* __restrict__ xt) {
  __shared__ u16 t[4096];
  const int tid = threadIdx.x;
  const int b = blockIdx.z;
  const int n0 = blockIdx.x * 64;
  const int c0 = blockIdx.y * 64;
  const int nl = (tid & 15) * 4;
  const int cl = tid >> 4;
#pragma unroll
  for (int r = 0; r < 4; r++) {
    const int c = cl + r * 16;
    const float4 v = *(const float4*)(x + ((long)b * 512 + c0 + c) * 4096 + n0 + nl);
    t[sw_idx(nl + 0, c)] = f2b(v.x);
    t[sw_idx(nl + 1, c)] = f2b(v.y);
    t[sw_idx(nl + 2, c)] = f2b(v.z);
    t[sw_idx(nl + 3, c)] = f2b(v.w);
  }
  __syncthreads();
  const int cw = (tid & 15) * 4;
#pragma unroll
  for (int r = 0; r < 4; r++) {
    const int n = cl + r * 16;
    const u16* tp = &t[sw_idx(n, cw)];
    ushort4 o; o.x = tp[0]; o.y = tp[1]; o.z = tp[2]; o.w = tp[3];
    *(ushort4*)(xt + ((long)b * 4096 + n0 + n) * 512 + c0 + cw) = o;
  }
}

// ---------------------------------------------------------------------------
// kvctx: per (b, h): C[128ch][128n] = wkv_r_h @ xt^T  (m97 K-loop, both gld16),
// then exp(k-half) -> LDS [d][n] / [e][n] bf16 (+ ones row 64, zero 65..79),
// PV MFMA ctx_partial[64 d][80 e] accumulated over 2 n-tiles, atomicAdd to
// ctx[bh][d][80] fp32 (col 64 = rsum). grid (16, 8, 8).
// ---------------------------------------------------------------------------
__global__ __launch_bounds__(256) void kvctx(const u16* __restrict__ wkv_r,
                                             const u16* __restrict__ xt,
                                             float* __restrict__ ctx) {
  __shared__ char smem[39168];
  u16* As = (u16*)smem;            // 128x32 u16 (8 KB)   } aliased with EV
  u16* Bs = (u16*)(smem + 8192);   // 128x32 u16 (8 KB)   }
  u16* EV = (u16*)smem;            // E: d*136+n ; V: 8704 + e*136+n (u16 idx)

  const int tid = threadIdx.x;
  const int wid = tid >> 6;
  const int lane = tid & 63;
  const int wm = wid >> 1, wn = wid & 1;
  const int gn0 = blockIdx.x, h = blockIdx.y, b = blockIdx.z;

  const u16* Ab = wkv_r + (long)h * 128 * 512;
  const int mr = lane & 15;
  const int quad = lane >> 4;
  const int q8 = quad * 8;
  const int nvt = (wn == 0) ? 3 : 2;

  f32x4 pv[2][3] = {};

  for (int t = 0; t < 2; t++) {
    const int n0 = gn0 * 256 + t * 128;
    const u16* Bb = xt + ((long)b * 4096 + n0) * 512;
    f32x4 acc[4][4] = {};

    for (int kk = 0; kk < 512; kk += 32) {
      __syncthreads();
#pragma unroll
      for (int i = 0; i < 2; i++) {
        const int slot = i * 256 + tid;
        const int row = slot >> 2;
        const int kc = (slot & 3) * 8;
        gld16((char*)As + i * 4096 + wid * 1024, Ab + (long)row * 512 + kk + kc);
        gld16((char*)Bs + i * 4096 + wid * 1024, Bb + (long)row * 512 + kk + kc);
      }
      __syncthreads();
      bf16x8 af[4], bfv[4];
#pragma unroll
      for (int i = 0; i < 4; i++)
        af[i] = *(const bf16x8*)(As + (wm * 64 + i * 16 + mr) * 32 + q8);
#pragma unroll
      for (int j = 0; j < 4; j++)
        bfv[j] = *(const bf16x8*)(Bs + (wn * 64 + j * 16 + mr) * 32 + q8);
#pragma unroll
      for (int i = 0; i < 4; i++)
#pragma unroll
        for (int j = 0; j < 4; j++)
          acc[i][j] = __builtin_amdgcn_mfma_f32_16x16x32_bf16(af[i], bfv[j], acc[i][j], 0, 0, 0);
    }

    // --- epilogue: C -> E (exp of k-half) / V in LDS, then PV MFMA ---
    __syncthreads();
    {
      // V rows 64..79: row 64 = ones (rsum channel), 65..79 = zeros
      const int rr = tid >> 4;
      const unsigned fill = (rr == 0) ? 0x3F803F80u : 0u;
      uint4 z; z.x = fill; z.y = fill; z.z = fill; z.w = fill;
      *(uint4*)((char*)smem + 17408 + (64 + rr) * 272 + (tid & 15) * 16) = z;
    }
    {
      const int base = (wm == 0) ? 0 : 8704;   // E or V region
#pragma unroll
      for (int i = 0; i < 4; i++)
#pragma unroll
        for (int j = 0; j < 4; j++) {
          const int nc = wn * 64 + j * 16 + mr;
#pragma unroll
          for (int r = 0; r < 4; r++) {
            const int row = i * 16 + quad * 4 + r;
            const float v = (wm == 0) ? __expf(acc[i][j][r]) : acc[i][j][r];
            EV[base + row * 136 + nc] = f2b(v);
          }
        }
    }
    __syncthreads();
#pragma unroll
    for (int ks = 0; ks < 4; ks++) {
      bf16x8 ef[2], vf[3];
#pragma unroll
      for (int tt = 0; tt < 2; tt++)
        ef[tt] = *(const bf16x8*)(EV + ((wm * 2 + tt) * 16 + mr) * 136 + ks * 32 + q8);
      for (int u = 0; u < nvt; u++) {
        const int te = (wn == 0) ? u : 3 + u;
        vf[u] = *(const bf16x8*)(EV + 8704 + (te * 16 + mr) * 136 + ks * 32 + q8);
      }
#pragma unroll
      for (int tt = 0; tt < 2; tt++)
        for (int u = 0; u < nvt; u++)
          pv[tt][u] = __builtin_amdgcn_mfma_f32_16x16x32_bf16(ef[tt], vf[u], pv[tt][u], 0, 0, 0);
    }
    // next t-iteration's first __syncthreads protects As/Bs overwrite vs EV reads
  }

  // --- accumulate partial ctx ---
  float* cb = ctx + ((long)(b * 8 + h) * 64) * 80;
#pragma unroll
  for (int tt = 0; tt < 2; tt++)
    for (int u = 0; u < nvt; u++) {
      const int te = (wn == 0) ? u : 3 + u;
      const int e = te * 16 + mr;
#pragma unroll
      for (int r = 0; r < 4; r++) {
        const int d = (wm * 2 + tt) * 16 + quad * 4 + r;
        atomicAdd(cb + (long)d * 80 + e, pv[tt][u][r]);
      }
    }
}

// ---------------------------------------------------------------------------
// Wc[b][o][h*64+d] = (sum_e w_out[o][h*64+e] * ctx[bh][d][e]) / ctx[bh][d][64]
// ---------------------------------------------------------------------------
__global__ __launch_bounds__(256) void wc_kern(const float* __restrict__ ctxp,
                                               const float* __restrict__ wout,
                                               u16* __restrict__ Wc) {
  __shared__ float cs[64 * 65];
  const int tid = threadIdx.x;
  const int bh = blockIdx.x, og = blockIdx.y;
  const int b = bh >> 3, h = bh & 7;
  const float* cbase = ctxp + (long)bh * 64 * 80;
  for (int i = tid; i < 4096; i += 256) {
    const int d = i >> 6, e = i & 63;
    cs[e * 65 + d] = cbase[d * 80 + e] / cbase[d * 80 + 64];
  }
  __syncthreads();
  const int d = tid & 63;
  const int o0 = og * 128 + (tid >> 6) * 32;
  float csr[64];
#pragma unroll
  for (int e = 0; e < 64; e++) csr[e] = cs[e * 65 + d];
  u16* wcp = Wc + (long)b * 512 * 512;
  for (int rr = 0; rr < 32; rr++) {
    const int o = o0 + rr;
    const float* wrow = wout + (long)o * 512 + h * 64;
    float a0 = 0.f, a1 = 0.f, a2 = 0.f, a3 = 0.f;
#pragma unroll
    for (int e = 0; e < 64; e += 4) {
      a0 += wrow[e + 0] * csr[e + 0];
      a1 += wrow[e + 1] * csr[e + 1];
      a2 += wrow[e + 2] * csr[e + 2];
      a3 += wrow[e + 3] * csr[e + 3];
    }
    wcp[(long)o * 512 + h * 64 + d] = f2b((a0 + a1) + (a2 + a3));
  }
}

// ---------------------------------------------------------------------------
// Weff[b][o][i] = 0.125 * sum_ch Wc[b][o][ch] * wqT[i][ch].  grid (4, 4, 8).
// ---------------------------------------------------------------------------
__global__ __launch_bounds__(256) void weff_gemm(const u16* __restrict__ Wc,
                                                 const u16* __restrict__ wqT,
                                                 u16* __restrict__ Weff) {
  __shared__ u16 As[128 * 32];
  __shared__ u16 Bs[128 * 32];
  const int tid = threadIdx.x;
  const int wid = tid >> 6;
  const int lane = tid & 63;
  const int wm = wid >> 1, wn = wid & 1;
  const int gn = blockIdx.x, gm = blockIdx.y, b = blockIdx.z;

  const u16* Ab = Wc + (long)b * 512 * 512 + (long)gm * 128 * 512;
  const u16* Bb = wqT + (long)gn * 128 * 512;

  f32x4 acc[4][4] = {};
  const int q8 = (lane >> 4) * 8;
  const int mr = lane & 15;

  for (int kk = 0; kk < 512; kk += 32) {
    __syncthreads();
#pragma unroll
    for (int i = 0; i < 2; i++) {
      const int slot = i * 256 + tid;
      const int row = slot >> 2;
      const int kc = (slot & 3) * 8;
      gld16((char*)As + i * 4096 + wid * 1024, Ab + (long)row * 512 + kk + kc);
      gld16((char*)Bs + i * 4096 + wid * 1024, Bb + (long)row * 512 + kk + kc);
    }
    __syncthreads();
    bf16x8 af[4], bfv[4];
#pragma unroll
    for (int i = 0; i < 4; i++)
      af[i] = *(const bf16x8*)(As + (wm * 64 + i * 16 + mr) * 32 + q8);
#pragma unroll
    for (int j = 0; j < 4; j++)
      bfv[j] = *(const bf16x8*)(Bs + (wn * 64 + j * 16 + mr) * 32 + q8);
#pragma unroll
    for (int i = 0; i < 4; i++)
#pragma unroll
      for (int j = 0; j < 4; j++)
        acc[i][j] = __builtin_amdgcn_mfma_f32_16x16x32_bf16(af[i], bfv[j], acc[i][j], 0, 0, 0);
  }

  const int col = lane & 15;
  const int quad = lane >> 4;
  u16* wb = Weff + (long)b * 512 * 512;
#pragma unroll
  for (int i = 0; i < 4; i++)
#pragma unroll
    for (int r = 0; r < 4; r++) {
      const int grow = gm * 128 + wm * 64 + i * 16 + quad * 4 + r;
#pragma unroll
      for (int j = 0; j < 4; j++) {
        const int gcol = gn * 128 + wn * 64 + j * 16 + col;
        wb[(long)grow * 512 + gcol] = f2b(acc[i][j][r] * 0.125f);
      }
    }
}

// ---------------------------------------------------------------------------
// out_gemm: out[b][o][n] = sum_i Weff[b][o][i] * xt[b][n][i] + bias[o]
// pure m97: both operands gld16. grid (32, 4, 8).
// ---------------------------------------------------------------------------
__global__ __launch_bounds__(256) void out_gemm(const u16* __restrict__ Weff,
                                                const u16* __restrict__ xt,
                                                const float* __restrict__ bias,
                                                float* __restrict__ outp) {
  __shared__ u16 As[128 * 32];
  __shared__ u16 Bs[128 * 32];
  const int tid = threadIdx.x;
  const int wid = tid >> 6;
  const int lane = tid & 63;
  const int wm = wid >> 1, wn = wid & 1;
  const int gn = blockIdx.x, gm = blockIdx.y, b = blockIdx.z;

  const u16* Ab = Weff + (long)b * 512 * 512 + (long)gm * 128 * 512;
  const u16* Bb = xt + ((long)b * 4096 + (long)gn * 128) * 512;

  f32x4 acc[4][4] = {};
  const int q8 = (lane >> 4) * 8;
  const int mr = lane & 15;

  for (int kk = 0; kk < 512; kk += 32) {
    __syncthreads();
#pragma unroll
    for (int i = 0; i < 2; i++) {
      const int slot = i * 256 + tid;
      const int row = slot >> 2;
      const int kc = (slot & 3) * 8;
      gld16((char*)As + i * 4096 + wid * 1024, Ab + (long)row * 512 + kk + kc);
      gld16((char*)Bs + i * 4096 + wid * 1024, Bb + (long)row * 512 + kk + kc);
    }
    __syncthreads();
    bf16x8 af[4], bfv[4];
#pragma unroll
    for (int i = 0; i < 4; i++)
      af[i] = *(const bf16x8*)(As + (wm * 64 + i * 16 + mr) * 32 + q8);
#pragma unroll
    for (int j = 0; j < 4; j++)
      bfv[j] = *(const bf16x8*)(Bs + (wn * 64 + j * 16 + mr) * 32 + q8);
#pragma unroll
    for (int i = 0; i < 4; i++)
#pragma unroll
      for (int j = 0; j < 4; j++)
        acc[i][j] = __builtin_amdgcn_mfma_f32_16x16x32_bf16(af[i], bfv[j], acc[i][j], 0, 0, 0);
  }

  const int col = lane & 15;
  const int quad = lane >> 4;
#pragma unroll
  for (int i = 0; i < 4; i++)
#pragma unroll
    for (int r = 0; r < 4; r++) {
      const int grow = gm * 128 + wm * 64 + i * 16 + quad * 4 + r;
      const float bv = bias[grow];
#pragma unroll
      for (int j = 0; j < 4; j++) {
        const long gcol = (long)gn * 128 + wn * 64 + j * 16 + col;
        outp[((long)b * 512 + grow) * 4096 + gcol] = acc[i][j][r] + bv;
      }
    }
}

// ---------------------------------------------------------------------------
// launcher
// ---------------------------------------------------------------------------
extern "C" void kernel_launch(void* const* d_in, const int* in_sizes, int n_in,
                              void* d_out, int out_size, void* d_ws, size_t ws_size,
                              hipStream_t stream) {
  const float* x = (const float*)d_in[0];      // [8][512][4096]
  const float* w_qkv = (const float*)d_in[1];  // [1536][512]
  const float* w_out = (const float*)d_in[2];  // [512][512]
  const float* b_out = (const float*)d_in[3];  // [512]
  float* out = (float*)d_out;                  // [8][512][4096]
  char* ws = (char*)d_ws;

  u16* xt = (u16*)(ws + 0);                    // 32 MB  [b][n][512] bf16
  u16* wkv_r = (u16*)(ws + 33554432);          //  1 MB  [h][{k64|v64}][512] bf16
  u16* wqT = (u16*)(ws + 34603008);            // .5 MB  Wq^T bf16 [i][ch]
  u16* wc = (u16*)(ws + 35127296);             //  4 MB  Wc bf16 [b][o][ch]
  u16* weff = (u16*)(ws + 39321600);           //  4 MB  Weff bf16 [b][o][i]
  float* ctx = (float*)(ws + 43515904);        // 1.25MB [bh][64 d][80] (e<64: ctx, 64: rsum)

  prep<<<896, 256, 0, stream>>>(w_qkv, wkv_r, wqT, ctx);
  xt_kern<<<dim3(64, 8, 8), 256, 0, stream>>>(x, xt);
  kvctx<<<dim3(16, 8, 8), 256, 0, stream>>>(wkv_r, xt, ctx);
  wc_kern<<<dim3(64, 4), 256, 0, stream>>>(ctx, w_out, wc);
  weff_gemm<<<dim3(4, 4, 8), 256, 0, stream>>>(wc, wqT, weff);
  out_gemm<<<dim3(32, 4, 8), 256, 0, stream>>>(weff, xt, b_out, out);
}

// Round 5
// 274.861 us; speedup vs baseline: 2.4499x; 2.4499x over previous
//
#include <hip/hip_runtime.h>
#include <hip/hip_bf16.h>
#include <cstdint>

typedef unsigned short u16;
typedef __attribute__((ext_vector_type(8))) short bf16x8;
typedef __attribute__((ext_vector_type(4))) float f32x4;

__device__ __forceinline__ u16 f2b(float f) {
  union { float f; unsigned u; } x; x.f = f;
  unsigned r = x.u + 0x7fffu + ((x.u >> 16) & 1u);   // RNE
  return (u16)(r >> 16);
}
__device__ __forceinline__ float b2f(u16 u) {
  union { unsigned u; float f; } x; x.u = ((unsigned)u) << 16;
  return x.f;
}
__device__ __forceinline__ void gld16(void* lds, const void* g) {
  __builtin_amdgcn_global_load_lds((const __attribute__((address_space(1))) void*)g,
                                   (__attribute__((address_space(3))) void*)lds, 16, 0, 0);
}
__device__ __forceinline__ int sw_idx(int n, int c) {
  return n * 64 + ((((c >> 2) ^ (n >> 2)) & 15) << 2) + (c & 3);
}

// ---------------------------------------------------------------------------
// prep: blk<512 : convert w_qkv rows 512..1535 -> wkv bf16 [1024][512]
//       blk<576 : transpose-convert w_qkv rows 0..511 -> wqT bf16 [i][ch]
//       else    : zero ctx+rsum (266240 floats)
// ---------------------------------------------------------------------------
__global__ __launch_bounds__(256) void prep(const float* __restrict__ w_qkv,
                                            u16* __restrict__ wkv,
                                            u16* __restrict__ wqT,
                                            float* __restrict__ zbuf) {
  const int tid = threadIdx.x;
  const int blk = blockIdx.x;
  if (blk < 512) {
    const int i = blk * 1024 + tid * 4;
    const float4 v = *(const float4*)(w_qkv + 262144 + i);
    ushort4 r; r.x = f2b(v.x); r.y = f2b(v.y); r.z = f2b(v.z); r.w = f2b(v.w);
    *(ushort4*)(wkv + i) = r;
  } else if (blk < 576) {
    __shared__ u16 t[4096];
    const int bb = blk - 512;
    const int i0 = (bb & 7) * 64;
    const int c0 = (bb >> 3) * 64;
    const int il = (tid & 15) * 4;
    const int cl = tid >> 4;
#pragma unroll
    for (int r = 0; r < 4; r++) {
      const int c = cl + r * 16;
      const float4 v = *(const float4*)(w_qkv + (c0 + c) * 512 + i0 + il);
      t[sw_idx(il + 0, c)] = f2b(v.x);
      t[sw_idx(il + 1, c)] = f2b(v.y);
      t[sw_idx(il + 2, c)] = f2b(v.z);
      t[sw_idx(il + 3, c)] = f2b(v.w);
    }
    __syncthreads();
    const int cw = (tid & 15) * 4;
#pragma unroll
    for (int r = 0; r < 4; r++) {
      const int i = cl + r * 16;
      const u16* tp = &t[sw_idx(i, cw)];
      ushort4 o; o.x = tp[0]; o.y = tp[1]; o.z = tp[2]; o.w = tp[3];
      *(ushort4*)(wqT + (i0 + i) * 512 + c0 + cw) = o;
    }
  } else {
    const int zi = (blk - 576) * 1024 + tid * 4;
    if (zi < 266240) *(float4*)(zbuf + zi) = float4{0.f, 0.f, 0.f, 0.f};
  }
}

// ---------------------------------------------------------------------------
// xt: transpose-convert x [b][512][4096] fp32 -> xt [b][4096][512] bf16
// ---------------------------------------------------------------------------
__global__ __launch_bounds__(256) void xt_kern(const float* __restrict__ x,
                                               u16* __restrict__ xt) {
  __shared__ u16 t[4096];
  const int tid = threadIdx.x;
  const int b = blockIdx.z;
  const int n0 = blockIdx.x * 64;
  const int c0 = blockIdx.y * 64;
  const int nl = (tid & 15) * 4;
  const int cl = tid >> 4;
#pragma unroll
  for (int r = 0; r < 4; r++) {
    const int c = cl + r * 16;
    const float4 v = *(const float4*)(x + ((long)b * 512 + c0 + c) * 4096 + n0 + nl);
    t[sw_idx(nl + 0, c)] = f2b(v.x);
    t[sw_idx(nl + 1, c)] = f2b(v.y);
    t[sw_idx(nl + 2, c)] = f2b(v.z);
    t[sw_idx(nl + 3, c)] = f2b(v.w);
  }
  __syncthreads();
  const int cw = (tid & 15) * 4;
#pragma unroll
  for (int r = 0; r < 4; r++) {
    const int n = cl + r * 16;
    const u16* tp = &t[sw_idx(n, cw)];
    ushort4 o; o.x = tp[0]; o.y = tp[1]; o.z = tp[2]; o.w = tp[3];
    *(ushort4*)(xt + ((long)b * 4096 + n0 + n) * 512 + c0 + cw) = o;
  }
}

// ---------------------------------------------------------------------------
// kv_gemm: pure m97. kv[ch][n] = wkv[ch][:] . xt[n][:], C-natural epilogue.
// k-channels (gm<4): store exp(val) bf16 and atomically accumulate row sums
// (register shuffle reduce, one atomic per row-half per wave). v: plain bf16.
// grid (32, 8, 8).
// ---------------------------------------------------------------------------
__global__ __launch_bounds__(256) void kv_gemm(const u16* __restrict__ wkv,
                                               const u16* __restrict__ xt,
                                               u16* __restrict__ kv,
                                               float* __restrict__ rsum) {
  __shared__ u16 As[128 * 32];
  __shared__ u16 Bs[128 * 32];
  const int tid = threadIdx.x;
  const int wid = tid >> 6;
  const int lane = tid & 63;
  const int wm = wid >> 1, wn = wid & 1;
  const int gn = blockIdx.x, gm = blockIdx.y, b = blockIdx.z;

  const u16* Ab = wkv + (long)gm * 128 * 512;
  const u16* Bb = xt + ((long)b * 4096 + (long)gn * 128) * 512;

  f32x4 acc[4][4] = {};
  const int q8 = (lane >> 4) * 8;
  const int mr = lane & 15;

  for (int kk = 0; kk < 512; kk += 32) {
    __syncthreads();
#pragma unroll
    for (int i = 0; i < 2; i++) {
      const int slot = i * 256 + tid;
      const int row = slot >> 2;
      const int kc = (slot & 3) * 8;
      gld16((char*)As + i * 4096 + wid * 1024, Ab + (long)row * 512 + kk + kc);
      gld16((char*)Bs + i * 4096 + wid * 1024, Bb + (long)row * 512 + kk + kc);
    }
    __syncthreads();
    bf16x8 af[4], bfv[4];
#pragma unroll
    for (int i = 0; i < 4; i++)
      af[i] = *(const bf16x8*)(As + (wm * 64 + i * 16 + mr) * 32 + q8);
#pragma unroll
    for (int j = 0; j < 4; j++)
      bfv[j] = *(const bf16x8*)(Bs + (wn * 64 + j * 16 + mr) * 32 + q8);
#pragma unroll
    for (int i = 0; i < 4; i++)
#pragma unroll
      for (int j = 0; j < 4; j++)
        acc[i][j] = __builtin_amdgcn_mfma_f32_16x16x32_bf16(af[i], bfv[j], acc[i][j], 0, 0, 0);
  }

  const int quad = lane >> 4;
  const bool isK = (gm < 4);
  u16* outb = kv + (long)b * 1024 * 4096;
#pragma unroll
  for (int i = 0; i < 4; i++) {
#pragma unroll
    for (int r = 0; r < 4; r++) {
      const int grow = gm * 128 + wm * 64 + i * 16 + quad * 4 + r;
      u16* rowp = outb + (long)grow * 4096 + gn * 128 + wn * 64 + mr;
      float s = 0.f;
#pragma unroll
      for (int j = 0; j < 4; j++) {
        float v = acc[i][j][r];
        if (isK) v = __expf(v);
        const u16 bv = f2b(v);
        rowp[j * 16] = bv;
        if (isK) s += b2f(bv);   // sum the rounded value for consistency
      }
      if (isK) {
        s += __shfl_xor(s, 1);
        s += __shfl_xor(s, 2);
        s += __shfl_xor(s, 4);
        s += __shfl_xor(s, 8);
        if (mr == 0) atomicAdd(rsum + b * 512 + grow, s);
      }
    }
  }
}

// ---------------------------------------------------------------------------
// ctx_gemm: ctx[bh][d][e] += sum_n E[d][n] * V[e][n], MFMA over n.
// E = kv rows h*64+d (already exp'd), V = kv rows 512+h*64+e.
// grid (bh=64, kc=8): each block reduces 512 n. fp32 atomics into ctx.
// ---------------------------------------------------------------------------
__global__ __launch_bounds__(256) void ctx_gemm(const u16* __restrict__ kv,
                                                float* __restrict__ ctx) {
  __shared__ u16 Es[64 * 64];   // [d][64 n] 8 KB
  __shared__ u16 Vs[64 * 64];   // [e][64 n] 8 KB
  const int tid = threadIdx.x;
  const int wid = tid >> 6;
  const int lane = tid & 63;
  const int wm = wid >> 1, wn = wid & 1;
  const int bh = blockIdx.x, kc = blockIdx.y;
  const int b = bh >> 3, h = bh & 7;

  const u16* Eg = kv + ((long)b * 1024 + h * 64) * 4096 + kc * 512;
  const u16* Vg = kv + ((long)b * 1024 + 512 + h * 64) * 4096 + kc * 512;

  const int mr = lane & 15;
  const int quad = lane >> 4;
  const int q8 = quad * 8;

  f32x4 acc[2][2] = {};

  for (int nn = 0; nn < 512; nn += 64) {
    __syncthreads();
#pragma unroll
    for (int c = 0; c < 2; c++) {
      const int off = c * 4096 + wid * 1024 + lane * 16;  // LDS byte offset covered
      const int row = off >> 7;
      const int cu = (off & 127) >> 1;
      gld16((char*)Es + c * 4096 + wid * 1024, Eg + (long)row * 4096 + nn + cu);
      gld16((char*)Vs + c * 4096 + wid * 1024, Vg + (long)row * 4096 + nn + cu);
    }
    __syncthreads();
#pragma unroll
    for (int ks = 0; ks < 2; ks++) {
      bf16x8 ef[2], vf[2];
#pragma unroll
      for (int ii = 0; ii < 2; ii++)
        ef[ii] = *(const bf16x8*)(Es + (wm * 32 + ii * 16 + mr) * 64 + ks * 32 + q8);
#pragma unroll
      for (int jj = 0; jj < 2; jj++)
        vf[jj] = *(const bf16x8*)(Vs + (wn * 32 + jj * 16 + mr) * 64 + ks * 32 + q8);
#pragma unroll
      for (int ii = 0; ii < 2; ii++)
#pragma unroll
        for (int jj = 0; jj < 2; jj++)
          acc[ii][jj] = __builtin_amdgcn_mfma_f32_16x16x32_bf16(ef[ii], vf[jj], acc[ii][jj], 0, 0, 0);
    }
  }

  float* cb = ctx + (long)bh * 4096;
#pragma unroll
  for (int ii = 0; ii < 2; ii++)
#pragma unroll
    for (int jj = 0; jj < 2; jj++)
#pragma unroll
      for (int r = 0; r < 4; r++) {
        const int d = wm * 32 + ii * 16 + quad * 4 + r;
        const int e = wn * 32 + jj * 16 + mr;
        atomicAdd(cb + d * 64 + e, acc[ii][jj][r]);
      }
}

// ---------------------------------------------------------------------------
// Wc[b][o][h*64+d] = (sum_e w_out[o][h*64+e] * ctx[bh][d][e]) / rsum[bh*64+d]
// ---------------------------------------------------------------------------
__global__ __launch_bounds__(256) void wc_kern(const float* __restrict__ ctxp,
                                               const float* __restrict__ rsump,
                                               const float* __restrict__ wout,
                                               u16* __restrict__ Wc) {
  __shared__ float cs[64 * 65];
  const int tid = threadIdx.x;
  const int bh = blockIdx.x, og = blockIdx.y;
  const int b = bh >> 3, h = bh & 7;
  for (int i = tid; i < 4096; i += 256) {
    const int d = i >> 6, e = i & 63;
    cs[e * 65 + d] = ctxp[(long)bh * 4096 + i] / rsump[(long)bh * 64 + d];
  }
  __syncthreads();
  const int d = tid & 63;
  const int o0 = og * 128 + (tid >> 6) * 32;
  float csr[64];
#pragma unroll
  for (int e = 0; e < 64; e++) csr[e] = cs[e * 65 + d];
  u16* wcp = Wc + (long)b * 512 * 512;
  for (int rr = 0; rr < 32; rr++) {
    const int o = o0 + rr;
    const float* wrow = wout + (long)o * 512 + h * 64;
    float a0 = 0.f, a1 = 0.f, a2 = 0.f, a3 = 0.f;
#pragma unroll
    for (int e = 0; e < 64; e += 4) {
      a0 += wrow[e + 0] * csr[e + 0];
      a1 += wrow[e + 1] * csr[e + 1];
      a2 += wrow[e + 2] * csr[e + 2];
      a3 += wrow[e + 3] * csr[e + 3];
    }
    wcp[(long)o * 512 + h * 64 + d] = f2b((a0 + a1) + (a2 + a3));
  }
}

// ---------------------------------------------------------------------------
// Weff[b][o][i] = 0.125 * sum_ch Wc[b][o][ch] * wqT[i][ch].  grid (4, 4, 8).
// ---------------------------------------------------------------------------
__global__ __launch_bounds__(256) void weff_gemm(const u16* __restrict__ Wc,
                                                 const u16* __restrict__ wqT,
                                                 u16* __restrict__ Weff) {
  __shared__ u16 As[128 * 32];
  __shared__ u16 Bs[128 * 32];
  const int tid = threadIdx.x;
  const int wid = tid >> 6;
  const int lane = tid & 63;
  const int wm = wid >> 1, wn = wid & 1;
  const int gn = blockIdx.x, gm = blockIdx.y, b = blockIdx.z;

  const u16* Ab = Wc + (long)b * 512 * 512 + (long)gm * 128 * 512;
  const u16* Bb = wqT + (long)gn * 128 * 512;

  f32x4 acc[4][4] = {};
  const int q8 = (lane >> 4) * 8;
  const int mr = lane & 15;

  for (int kk = 0; kk < 512; kk += 32) {
    __syncthreads();
#pragma unroll
    for (int i = 0; i < 2; i++) {
      const int slot = i * 256 + tid;
      const int row = slot >> 2;
      const int kc = (slot & 3) * 8;
      gld16((char*)As + i * 4096 + wid * 1024, Ab + (long)row * 512 + kk + kc);
      gld16((char*)Bs + i * 4096 + wid * 1024, Bb + (long)row * 512 + kk + kc);
    }
    __syncthreads();
    bf16x8 af[4], bfv[4];
#pragma unroll
    for (int i = 0; i < 4; i++)
      af[i] = *(const bf16x8*)(As + (wm * 64 + i * 16 + mr) * 32 + q8);
#pragma unroll
    for (int j = 0; j < 4; j++)
      bfv[j] = *(const bf16x8*)(Bs + (wn * 64 + j * 16 + mr) * 32 + q8);
#pragma unroll
    for (int i = 0; i < 4; i++)
#pragma unroll
      for (int j = 0; j < 4; j++)
        acc[i][j] = __builtin_amdgcn_mfma_f32_16x16x32_bf16(af[i], bfv[j], acc[i][j], 0, 0, 0);
  }

  const int col = lane & 15;
  const int quad = lane >> 4;
  u16* wb = Weff + (long)b * 512 * 512;
#pragma unroll
  for (int i = 0; i < 4; i++)
#pragma unroll
    for (int r = 0; r < 4; r++) {
      const int grow = gm * 128 + wm * 64 + i * 16 + quad * 4 + r;
#pragma unroll
      for (int j = 0; j < 4; j++) {
        const int gcol = gn * 128 + wn * 64 + j * 16 + col;
        wb[(long)grow * 512 + gcol] = f2b(acc[i][j][r] * 0.125f);
      }
    }
}

// ---------------------------------------------------------------------------
// out_gemm: out[b][o][n] = sum_i Weff[b][o][i] * xt[b][n][i] + bias[o]
// pure m97: both operands gld16. grid (32, 4, 8).
// ---------------------------------------------------------------------------
__global__ __launch_bounds__(256) void out_gemm(const u16* __restrict__ Weff,
                                                const u16* __restrict__ xt,
                                                const float* __restrict__ bias,
                                                float* __restrict__ outp) {
  __shared__ u16 As[128 * 32];
  __shared__ u16 Bs[128 * 32];
  const int tid = threadIdx.x;
  const int wid = tid >> 6;
  const int lane = tid & 63;
  const int wm = wid >> 1, wn = wid & 1;
  const int gn = blockIdx.x, gm = blockIdx.y, b = blockIdx.z;

  const u16* Ab = Weff + (long)b * 512 * 512 + (long)gm * 128 * 512;
  const u16* Bb = xt + ((long)b * 4096 + (long)gn * 128) * 512;

  f32x4 acc[4][4] = {};
  const int q8 = (lane >> 4) * 8;
  const int mr = lane & 15;

  for (int kk = 0; kk < 512; kk += 32) {
    __syncthreads();
#pragma unroll
    for (int i = 0; i < 2; i++) {
      const int slot = i * 256 + tid;
      const int row = slot >> 2;
      const int kc = (slot & 3) * 8;
      gld16((char*)As + i * 4096 + wid * 1024, Ab + (long)row * 512 + kk + kc);
      gld16((char*)Bs + i * 4096 + wid * 1024, Bb + (long)row * 512 + kk + kc);
    }
    __syncthreads();
    bf16x8 af[4], bfv[4];
#pragma unroll
    for (int i = 0; i < 4; i++)
      af[i] = *(const bf16x8*)(As + (wm * 64 + i * 16 + mr) * 32 + q8);
#pragma unroll
    for (int j = 0; j < 4; j++)
      bfv[j] = *(const bf16x8*)(Bs + (wn * 64 + j * 16 + mr) * 32 + q8);
#pragma unroll
    for (int i = 0; i < 4; i++)
#pragma unroll
      for (int j = 0; j < 4; j++)
        acc[i][j] = __builtin_amdgcn_mfma_f32_16x16x32_bf16(af[i], bfv[j], acc[i][j], 0, 0, 0);
  }

  const int col = lane & 15;
  const int quad = lane >> 4;
#pragma unroll
  for (int i = 0; i < 4; i++)
#pragma unroll
    for (int r = 0; r < 4; r++) {
      const int grow = gm * 128 + wm * 64 + i * 16 + quad * 4 + r;
      const float bv = bias[grow];
#pragma unroll
      for (int j = 0; j < 4; j++) {
        const long gcol = (long)gn * 128 + wn * 64 + j * 16 + col;
        outp[((long)b * 512 + grow) * 4096 + gcol] = acc[i][j][r] + bv;
      }
    }
}

// ---------------------------------------------------------------------------
// launcher
// ---------------------------------------------------------------------------
extern "C" void kernel_launch(void* const* d_in, const int* in_sizes, int n_in,
                              void* d_out, int out_size, void* d_ws, size_t ws_size,
                              hipStream_t stream) {
  const float* x = (const float*)d_in[0];      // [8][512][4096]
  const float* w_qkv = (const float*)d_in[1];  // [1536][512]
  const float* w_out = (const float*)d_in[2];  // [512][512]
  const float* b_out = (const float*)d_in[3];  // [512]
  float* out = (float*)d_out;                  // [8][512][4096]
  char* ws = (char*)d_ws;

  u16* xt = (u16*)(ws + 0);                    // 32 MB  [b][n][512] bf16
  u16* kv = (u16*)(ws + 33554432);             // 64 MB  [b][1024ch][4096n] bf16 (k rows hold exp)
  u16* wkv = (u16*)(ws + 100663296);           //  1 MB  w_qkv rows 512..1535 bf16
  u16* wqT = (u16*)(ws + 101711872);           // .5 MB  Wq^T bf16 [i][ch]
  u16* wc = (u16*)(ws + 102236160);            //  4 MB  Wc bf16 [b][o][ch]
  u16* weff = (u16*)(ws + 106430464);          //  4 MB  Weff bf16 [b][o][i]
  float* ctx = (float*)(ws + 110624768);       //  1 MB  [bh][d][e] fp32 (atomic)
  float* rsum = (float*)(ws + 111673344);      // 16 KB  [bh*64+d]   fp32 (atomic)

  prep<<<836, 256, 0, stream>>>(w_qkv, wkv, wqT, ctx);
  xt_kern<<<dim3(64, 8, 8), 256, 0, stream>>>(x, xt);
  kv_gemm<<<dim3(32, 8, 8), 256, 0, stream>>>(wkv, xt, kv, rsum);
  ctx_gemm<<<dim3(64, 8), 256, 0, stream>>>(kv, ctx);
  wc_kern<<<dim3(64, 4), 256, 0, stream>>>(ctx, rsum, w_out, wc);
  weff_gemm<<<dim3(4, 4, 8), 256, 0, stream>>>(wc, wqT, weff);
  out_gemm<<<dim3(32, 4, 8), 256, 0, stream>>>(weff, xt, b_out, out);
}